// Round 4
// baseline (240.686 us; speedup 1.0000x reference)
//
#include <hip/hip_runtime.h>

// One output row per thread: 8 threads cooperate on one 8x8 block, but with
// NO LDS and NO barriers -- they simply each read the whole block (the 8
// same-address lanes coalesce/broadcast into a single L1 request).
//
// Thread (block b, row i):  T[k] = sum_j M[j][i] * Q[j][k] * X[j][k]
//                           o[l] = 128 + sum_k T[k] * M[k][l]
//
// Per-thread live set: T[8] + mcol[8] + 4-row group (32) + addr ~= 55 VGPRs.
// This fits the 64-VGPR / 8-wave-per-SIMD budget with NO spills -- rounds
// 2-3 showed the 64-float-accumulator version spills through scratch at
// VGPR_Count 56-60 no matter what launch bounds allow (scratch-L2-bound,
// all HBM/VALU pipes idle).
//
// qt[] and stage-2 mtx[] accesses are wave-uniform -> scalar s_loads.
// mcol[j] = mtx[j*8+i] is lane-varying but a 256 B L1-resident table.

__global__ __launch_bounds__(256, 8) void bidct_kernel(
    const float* __restrict__ x, const float* __restrict__ qt,
    const float* __restrict__ mtx, float* __restrict__ out)
{
    const int n   = blockIdx.x * 256 + threadIdx.x;
    const int b   = n >> 3;            // 8x8 block id (8 consecutive lanes share)
    const int i   = n & 7;             // output row this thread produces
    const int img = b >> 14;           // 16384 blocks per 1024x1024 image
    const int m   = b & 16383;
    const int br  = m >> 7;            // block row 0..127
    const int bc  = m & 127;           // block col 0..127
    const size_t base = ((size_t)img << 20) + ((size_t)br << 13) + ((size_t)bc << 3);

    // Per-thread column of the DCT matrix: mcol[j] = M[j][i]
    float mcol[8];
#pragma unroll
    for (int j = 0; j < 8; ++j) mcol[j] = mtx[j * 8 + i];

    const float* __restrict__ px = x + base;

    // ---- Stage 1: T[k] = sum_j mcol[j] * (Q[j][k] * X[j][k]) ----
    float T[8] = {0.f, 0.f, 0.f, 0.f, 0.f, 0.f, 0.f, 0.f};
#pragma unroll
    for (int jh = 0; jh < 2; ++jh) {
        float4 xa[4], xb[4];
#pragma unroll
        for (int jj = 0; jj < 4; ++jj) {
            const float* row = px + (size_t)(jh * 4 + jj) * 1024;
            xa[jj] = *reinterpret_cast<const float4*>(row);
            xb[jj] = *reinterpret_cast<const float4*>(row + 4);
        }
#pragma unroll
        for (int jj = 0; jj < 4; ++jj) {
            const int j = jh * 4 + jj;
            const float mj = mcol[j];
            T[0] = fmaf(mj, xa[jj].x * qt[j * 8 + 0], T[0]);
            T[1] = fmaf(mj, xa[jj].y * qt[j * 8 + 1], T[1]);
            T[2] = fmaf(mj, xa[jj].z * qt[j * 8 + 2], T[2]);
            T[3] = fmaf(mj, xa[jj].w * qt[j * 8 + 3], T[3]);
            T[4] = fmaf(mj, xb[jj].x * qt[j * 8 + 4], T[4]);
            T[5] = fmaf(mj, xb[jj].y * qt[j * 8 + 5], T[5]);
            T[6] = fmaf(mj, xb[jj].z * qt[j * 8 + 6], T[6]);
            T[7] = fmaf(mj, xb[jj].w * qt[j * 8 + 7], T[7]);
        }
    }

    // ---- Stage 2: o[l] = 128 + sum_k T[k] * M[k][l] ----
    float o[8] = {128.f, 128.f, 128.f, 128.f, 128.f, 128.f, 128.f, 128.f};
#pragma unroll
    for (int k = 0; k < 8; ++k) {
        const float tk = T[k];
#pragma unroll
        for (int l = 0; l < 8; ++l)
            o[l] = fmaf(tk, mtx[k * 8 + l], o[l]);
    }

    float* row = out + base + (size_t)i * 1024;
    *reinterpret_cast<float4*>(row)     = make_float4(o[0], o[1], o[2], o[3]);
    *reinterpret_cast<float4*>(row + 4) = make_float4(o[4], o[5], o[6], o[7]);
}

extern "C" void kernel_launch(void* const* d_in, const int* in_sizes, int n_in,
                              void* d_out, int out_size, void* d_ws, size_t ws_size,
                              hipStream_t stream) {
    const float* x   = (const float*)d_in[0];
    const float* qt  = (const float*)d_in[1];
    const float* mtx = (const float*)d_in[2];
    float*       out = (float*)d_out;

    // out_size is in floats. 8 threads per 64-float block -> out_size/8 threads.
    const int grid = out_size / 2048;   // (out_size/8) / 256 = 16384 workgroups
    bidct_kernel<<<grid, 256, 0, stream>>>(x, qt, mtx, out);
}

// Round 5
// 231.142 us; speedup vs baseline: 1.0413x; 1.0413x over previous
//
#include <hip/hip_runtime.h>

// Wave-local LDS staging, zero barriers.
// Each WAVE owns an 8-row x 64-col stripe = 8 blocks (2 KB + pad in LDS).
// All LDS hazards are intra-wave (lockstep) -> compiler lgkmcnt waits only;
// no __syncthreads() anywhere (round 0 paid 3 full-drain barriers).
//
// Phase 1: dense copy global->LDS, 1 KB/instr (fixes round 4's 8x-redundant
//          VMEM: 18 instrs/wave @128B useful -> 4 instrs/wave @1KB).
// Phase 2: thread (bl,i) computes output row i of block bl from LDS
//          (8-lane same-address broadcast reads = conflict-free), dequant
//          folded here so qt[j*8+k] is wave-uniform -> scalar loads.
// Phase 3: row writeback to LDS. Row stride padded to 17 float4 (68 words,
//          68%32=4) -> banks (i*4+bl*8+w)%32 = uniform 2 words/bank per
//          16-lane phase = free. (Round 0's unpadded stride 64 f4 made the
//          bank index independent of i -> 16-way conflict, ~12 us.)
// Phase 4: dense copy LDS->global.

__global__ __launch_bounds__(256, 8) void bidct_kernel(
    const float* __restrict__ x, const float* __restrict__ qt,
    const float* __restrict__ mtx, float* __restrict__ out)
{
    __shared__ float4 tile4[4][136];   // per wave: 8 rows x 17 float4 (1 pad)

    const int wv = threadIdx.x >> 6;   // wave within workgroup
    const int l  = threadIdx.x & 63;   // lane
    float4* __restrict__ tw = tile4[wv];

    // wave stripe: image img, row group rg (8 rows), col group cg (64 cols)
    const int wid  = blockIdx.x * 4 + wv;        // 0..65535
    const int img  = wid >> 11;                  // 2048 stripes per image
    const int rest = wid & 2047;
    const int rg   = rest >> 4;                  // 0..127
    const int cg   = rest & 15;                  // 0..15
    const size_t base = ((size_t)img << 20) + ((size_t)rg << 13) + ((size_t)cg << 6);

    // ---- Phase 1: dense global -> LDS (padded) ----
#pragma unroll
    for (int r = 0; r < 2; ++r) {
        const int f  = r * 64 + l;               // 0..127
        const int j  = f >> 4;                   // row 0..7
        const int c4 = f & 15;                   // float4-col 0..15
        const float4 v = *reinterpret_cast<const float4*>(x + base + j * 1024 + c4 * 4);
        tw[j * 17 + c4] = v;
    }

    // ---- Phase 2: per-row IDCT with dequant folded in ----
    const int bl = l >> 3;                       // block 0..7 within stripe
    const int i  = l & 7;                        // output row within block

    float mcol[8];                               // M[j][i], lane-varying (L1 table)
#pragma unroll
    for (int j = 0; j < 8; ++j) mcol[j] = mtx[j * 8 + i];

    float T[8] = {0.f, 0.f, 0.f, 0.f, 0.f, 0.f, 0.f, 0.f};
#pragma unroll
    for (int j = 0; j < 8; ++j) {
        const float4 xa = tw[j * 17 + bl * 2];       // broadcast to 8 lanes
        const float4 xb = tw[j * 17 + bl * 2 + 1];
        const float mj = mcol[j];
        T[0] = fmaf(mj, xa.x * qt[j * 8 + 0], T[0]); // qt idx wave-uniform -> SGPR
        T[1] = fmaf(mj, xa.y * qt[j * 8 + 1], T[1]);
        T[2] = fmaf(mj, xa.z * qt[j * 8 + 2], T[2]);
        T[3] = fmaf(mj, xa.w * qt[j * 8 + 3], T[3]);
        T[4] = fmaf(mj, xb.x * qt[j * 8 + 4], T[4]);
        T[5] = fmaf(mj, xb.y * qt[j * 8 + 5], T[5]);
        T[6] = fmaf(mj, xb.z * qt[j * 8 + 6], T[6]);
        T[7] = fmaf(mj, xb.w * qt[j * 8 + 7], T[7]);
    }

    float o[8] = {128.f, 128.f, 128.f, 128.f, 128.f, 128.f, 128.f, 128.f};
#pragma unroll
    for (int k = 0; k < 8; ++k) {
        const float tk = T[k];
#pragma unroll
        for (int lcol = 0; lcol < 8; ++lcol)
            o[lcol] = fmaf(tk, mtx[k * 8 + lcol], o[lcol]);  // uniform -> SGPR
    }

    // ---- Phase 3: row writeback to LDS (padded -> conflict-free) ----
    tw[i * 17 + bl * 2]     = make_float4(o[0], o[1], o[2], o[3]);
    tw[i * 17 + bl * 2 + 1] = make_float4(o[4], o[5], o[6], o[7]);

    // ---- Phase 4: dense LDS -> global ----
#pragma unroll
    for (int r = 0; r < 2; ++r) {
        const int f  = r * 64 + l;
        const int j  = f >> 4;
        const int c4 = f & 15;
        *reinterpret_cast<float4*>(out + base + j * 1024 + c4 * 4) = tw[j * 17 + c4];
    }
}

extern "C" void kernel_launch(void* const* d_in, const int* in_sizes, int n_in,
                              void* d_out, int out_size, void* d_ws, size_t ws_size,
                              hipStream_t stream) {
    const float* x   = (const float*)d_in[0];
    const float* qt  = (const float*)d_in[1];
    const float* mtx = (const float*)d_in[2];
    float*       out = (float*)d_out;

    // out_size in floats; each workgroup (4 waves) covers 4 stripes = 2048 floats
    const int grid = out_size / 2048;   // 16384 workgroups
    bidct_kernel<<<grid, 256, 0, stream>>>(x, qt, mtx, out);
}

// Round 7
// 230.077 us; speedup vs baseline: 1.0461x; 1.0046x over previous
//
#include <hip/hip_runtime.h>

// Wave-local LDS staging, zero barriers, NON-TEMPORAL output stores.
//
// Each WAVE owns an 8-row x 64-col stripe = 8 blocks (2 KB + pad in LDS).
// All LDS hazards are intra-wave (lockstep) -> compiler lgkmcnt waits only;
// no __syncthreads() anywhere.
//
// Round-5 result: conflict-free, barrier-free, spill-free version still runs
// ~79 us = 2.5 TB/s HBM -- same as every other structure. Theory: L2/L3
// write-allocate thrash. out (134 MB/iter, never re-read) allocates dirty
// lines in L2+L3; combined 268 MB/iter insert+evict against 256 MB L3 is
// maximal thrash and evicts the x lines that would otherwise hit (FETCH
// shows only 50% read hit). Fix: stream the output with nt stores (no
// cache allocation, like the 6.7 TB/s fill); keep loads cached for L3 hits.
//
// NOTE round 6: __builtin_nontemporal_store requires a NATIVE clang vector
// type, not HIP_vector_type<float,4> -> use ext_vector_type(4).
//
// Phase 1: dense copy global->LDS, 1 KB/wave-instr.
// Phase 2: thread (bl,i) computes output row i of block bl from LDS
//          (8-lane same-address broadcast reads = conflict-free), dequant
//          folded here so qt[j*8+k] is wave-uniform -> scalar loads.
// Phase 3: row writeback to LDS, stride padded to 17 float4 -> conflict-free.
// Phase 4: dense LDS->global with __builtin_nontemporal_store (nt flag).

typedef float f32x4 __attribute__((ext_vector_type(4)));

__global__ __launch_bounds__(256, 8) void bidct_kernel(
    const float* __restrict__ x, const float* __restrict__ qt,
    const float* __restrict__ mtx, float* __restrict__ out)
{
    __shared__ float4 tile4[4][136];   // per wave: 8 rows x 17 float4 (1 pad)

    const int wv = threadIdx.x >> 6;   // wave within workgroup
    const int l  = threadIdx.x & 63;   // lane
    float4* __restrict__ tw = tile4[wv];

    // wave stripe: image img, row group rg (8 rows), col group cg (64 cols)
    const int wid  = blockIdx.x * 4 + wv;        // 0..65535
    const int img  = wid >> 11;                  // 2048 stripes per image
    const int rest = wid & 2047;
    const int rg   = rest >> 4;                  // 0..127
    const int cg   = rest & 15;                  // 0..15
    const size_t base = ((size_t)img << 20) + ((size_t)rg << 13) + ((size_t)cg << 6);

    // ---- Phase 1: dense global -> LDS (padded) ----
#pragma unroll
    for (int r = 0; r < 2; ++r) {
        const int f  = r * 64 + l;               // 0..127
        const int j  = f >> 4;                   // row 0..7
        const int c4 = f & 15;                   // float4-col 0..15
        const float4 v = *reinterpret_cast<const float4*>(x + base + j * 1024 + c4 * 4);
        tw[j * 17 + c4] = v;
    }

    // ---- Phase 2: per-row IDCT with dequant folded in ----
    const int bl = l >> 3;                       // block 0..7 within stripe
    const int i  = l & 7;                        // output row within block

    float mcol[8];                               // M[j][i], lane-varying (L1 table)
#pragma unroll
    for (int j = 0; j < 8; ++j) mcol[j] = mtx[j * 8 + i];

    float T[8] = {0.f, 0.f, 0.f, 0.f, 0.f, 0.f, 0.f, 0.f};
#pragma unroll
    for (int j = 0; j < 8; ++j) {
        const float4 xa = tw[j * 17 + bl * 2];       // broadcast to 8 lanes
        const float4 xb = tw[j * 17 + bl * 2 + 1];
        const float mj = mcol[j];
        T[0] = fmaf(mj, xa.x * qt[j * 8 + 0], T[0]); // qt idx wave-uniform -> SGPR
        T[1] = fmaf(mj, xa.y * qt[j * 8 + 1], T[1]);
        T[2] = fmaf(mj, xa.z * qt[j * 8 + 2], T[2]);
        T[3] = fmaf(mj, xa.w * qt[j * 8 + 3], T[3]);
        T[4] = fmaf(mj, xb.x * qt[j * 8 + 4], T[4]);
        T[5] = fmaf(mj, xb.y * qt[j * 8 + 5], T[5]);
        T[6] = fmaf(mj, xb.z * qt[j * 8 + 6], T[6]);
        T[7] = fmaf(mj, xb.w * qt[j * 8 + 7], T[7]);
    }

    float o[8] = {128.f, 128.f, 128.f, 128.f, 128.f, 128.f, 128.f, 128.f};
#pragma unroll
    for (int k = 0; k < 8; ++k) {
        const float tk = T[k];
#pragma unroll
        for (int lcol = 0; lcol < 8; ++lcol)
            o[lcol] = fmaf(tk, mtx[k * 8 + lcol], o[lcol]);  // uniform -> SGPR
    }

    // ---- Phase 3: row writeback to LDS (padded -> conflict-free) ----
    tw[i * 17 + bl * 2]     = make_float4(o[0], o[1], o[2], o[3]);
    tw[i * 17 + bl * 2 + 1] = make_float4(o[4], o[5], o[6], o[7]);

    // ---- Phase 4: dense LDS -> global, non-temporal (no L2/L3 allocate) ----
#pragma unroll
    for (int r = 0; r < 2; ++r) {
        const int f  = r * 64 + l;
        const int j  = f >> 4;
        const int c4 = f & 15;
        const float4 v = tw[j * 17 + c4];
        f32x4 nv; nv.x = v.x; nv.y = v.y; nv.z = v.z; nv.w = v.w;
        __builtin_nontemporal_store(nv,
            reinterpret_cast<f32x4*>(out + base + j * 1024 + c4 * 4));
    }
}

extern "C" void kernel_launch(void* const* d_in, const int* in_sizes, int n_in,
                              void* d_out, int out_size, void* d_ws, size_t ws_size,
                              hipStream_t stream) {
    const float* x   = (const float*)d_in[0];
    const float* qt  = (const float*)d_in[1];
    const float* mtx = (const float*)d_in[2];
    float*       out = (float*)d_out;

    // out_size in floats; each workgroup (4 waves) covers 4 stripes = 2048 floats
    const int grid = out_size / 2048;   // 16384 workgroups
    bidct_kernel<<<grid, 256, 0, stream>>>(x, qt, mtx, out);
}